// Round 1
// baseline (221.722 us; speedup 1.0000x reference)
//
#include <hip/hip_runtime.h>
#include <hip/hip_bf16.h>

// HistogramLoss: two [32,3,512,512] fp32 inputs, per-(B,C) 64-bin histogram
// over [0,1], normalized by row count (exactly 2^18), L1 mean of difference.
//
// Strategy: exact integer counting (bit-exact vs reference up to final float
// rounding). LDS sub-histograms per half-wave to reduce ds atomic same-address
// serialization; global u32 histogram in d_ws; tiny finalize kernel.

#define HW        262144      // 512*512, = 2^18
#define ROWS      96          // B*C per image
#define NBINS     64
#define BPR       16          // blocks per row
#define CHUNK     (HW / BPR)  // 16384 elements per block
#define THREADS   256
#define V4_PER_T  (CHUNK / 4 / THREADS)  // 16 float4 per thread
#define TOTAL_BC  (2 * ROWS * NBINS)     // 12288 hist entries

__global__ __launch_bounds__(THREADS)
void hist_kernel(const float* __restrict__ fake,
                 const float* __restrict__ real,
                 unsigned int* __restrict__ ghist) {
    // 8 sub-histograms (one per half-wave) to cut same-address atomic collisions
    __shared__ unsigned int h[8 * NBINS];
    const int tid = threadIdx.x;
    h[tid]       = 0u;
    h[tid + 256] = 0u;
    __syncthreads();

    const int b     = blockIdx.x;        // 0 .. 2*ROWS*BPR-1
    const int chunk = b % BPR;
    const int rowg  = b / BPR;           // 0..191: img*ROWS + row
    const float* src = (rowg < ROWS) ? fake : real;
    const int row    = (rowg < ROWS) ? rowg : (rowg - ROWS);

    const float4* __restrict__ p =
        (const float4*)(src + (size_t)row * HW + (size_t)chunk * CHUNK);

    unsigned int* hsub = &h[(tid >> 5) * NBINS];   // per half-wave

#pragma unroll
    for (int i = 0; i < V4_PER_T; ++i) {
        float4 v = p[i * THREADS + tid];
        // x in [0,1): bin = trunc(x*64), clamp top for safety
        int b0 = min((int)(v.x * 64.0f), 63);
        int b1 = min((int)(v.y * 64.0f), 63);
        int b2 = min((int)(v.z * 64.0f), 63);
        int b3 = min((int)(v.w * 64.0f), 63);
        atomicAdd(&hsub[b0], 1u);
        atomicAdd(&hsub[b1], 1u);
        atomicAdd(&hsub[b2], 1u);
        atomicAdd(&hsub[b3], 1u);
    }
    __syncthreads();

    if (tid < NBINS) {
        unsigned int s = 0;
#pragma unroll
        for (int k = 0; k < 8; ++k) s += h[k * NBINS + tid];
        atomicAdd(&ghist[rowg * NBINS + tid], s);
    }
}

__global__ __launch_bounds__(THREADS)
void loss_kernel(const unsigned int* __restrict__ ghist, float* __restrict__ out) {
    const int tid = threadIdx.x;
    int acc = 0;
    // fake hist at [0, 6144), real hist at [6144, 12288)
    for (int i = tid; i < ROWS * NBINS; i += THREADS) {
        int cf = (int)ghist[i];
        int cr = (int)ghist[ROWS * NBINS + i];
        int d  = cf - cr;
        acc += (d < 0) ? -d : d;
    }
    // wave reduce (64 lanes)
#pragma unroll
    for (int off = 32; off > 0; off >>= 1)
        acc += __shfl_down(acc, off, 64);
    __shared__ int wsum[4];
    if ((tid & 63) == 0) wsum[tid >> 6] = acc;
    __syncthreads();
    if (tid == 0) {
        int total = wsum[0] + wsum[1] + wsum[2] + wsum[3];
        // loss = sum|cf-cr| / (2^18 * ROWS*NBINS), computed in double, stored f32
        out[0] = (float)((double)total / (262144.0 * (double)(ROWS * NBINS)));
    }
}

extern "C" void kernel_launch(void* const* d_in, const int* in_sizes, int n_in,
                              void* d_out, int out_size, void* d_ws, size_t ws_size,
                              hipStream_t stream) {
    const float* fake = (const float*)d_in[0];
    const float* real = (const float*)d_in[1];
    unsigned int* ghist = (unsigned int*)d_ws;   // 2*96*64 u32 = 49152 B
    float* out = (float*)d_out;

    hipMemsetAsync(ghist, 0, TOTAL_BC * sizeof(unsigned int), stream);

    dim3 grid(2 * ROWS * BPR);   // 3072 blocks
    hist_kernel<<<grid, THREADS, 0, stream>>>(fake, real, ghist);
    loss_kernel<<<1, THREADS, 0, stream>>>(ghist, out);
}